// Round 2
// baseline (413.237 us; speedup 1.0000x reference)
//
#include <hip/hip_runtime.h>

// DotProductAttention: B=16, Q=K=2048, D=64, fp32 in/out, mask int32 (True -> -1e30).
// Flash attention, swapped-QK^T (S^T = K.Q^T) so softmax + O-accum are per-lane-q.
// bf16 32x32x16 MFMA; K and V^T staged in LDS (XOR swizzle); mask streamed directly
// from global in D-fragment order (L1 absorbs transpose); T14 reg prefetch.

#define Bn   16
#define Qn   2048
#define Kseq 2048
#define Dn   64
#define QBLK 128
#define NEGF (-1e30f)

typedef __attribute__((ext_vector_type(8)))  short short8;
typedef __attribute__((ext_vector_type(16))) float f32x16;

static __device__ __forceinline__ short f2bf(float x) {
  union { float f; unsigned u; } un; un.f = x;
  unsigned r = un.u + 0x7FFFu + ((un.u >> 16) & 1u);   // RNE
  return (short)(r >> 16);
}
static __device__ __forceinline__ unsigned pkbf(float lo, float hi) {
  unsigned r;
  asm("v_cvt_pk_bf16_f32 %0, %1, %2" : "=v"(r) : "v"(lo), "v"(hi));
  return r;
}
#if __has_builtin(__builtin_amdgcn_exp2f)
#define EXP2 __builtin_amdgcn_exp2f
#else
#define EXP2 exp2f
#endif
#define MFMA32 __builtin_amdgcn_mfma_f32_32x32x16_bf16

// ---- prefetch next KV tile (K: 2x8 fp32, V: 16 fp32 col-chunk) + next mask ----
#define PREFETCH(MNXT)                                                        \
  do {                                                                        \
    ka0 = *(const float4*)(kp);                                               \
    ka1 = *(const float4*)(kp + 4);                                           \
    kb0 = *(const float4*)(kp + 2048);                                        \
    kb1 = *(const float4*)(kp + 2052);                                        \
    _Pragma("unroll")                                                         \
    for (int j = 0; j < 16; ++j) vreg[j] = vp[j * 64];                        \
    _Pragma("unroll")                                                         \
    for (int g = 0; g < 8; ++g) MNXT[g] = mp[2 * g];                          \
    kp += 4096; vp += 4096; mp += 16;                                         \
  } while (0)

#define WRITELDS()                                                            \
  do {                                                                        \
    short8 t;                                                                 \
    t[0]=f2bf(ka0.x); t[1]=f2bf(ka0.y); t[2]=f2bf(ka0.z); t[3]=f2bf(ka0.w);   \
    t[4]=f2bf(ka1.x); t[5]=f2bf(ka1.y); t[6]=f2bf(ka1.z); t[7]=f2bf(ka1.w);   \
    *(short8*)kwa = t;                                                        \
    t[0]=f2bf(kb0.x); t[1]=f2bf(kb0.y); t[2]=f2bf(kb0.z); t[3]=f2bf(kb0.w);   \
    t[4]=f2bf(kb1.x); t[5]=f2bf(kb1.y); t[6]=f2bf(kb1.z); t[7]=f2bf(kb1.w);   \
    *(short8*)kwb = t;                                                        \
    short8 v0, v1;                                                            \
    _Pragma("unroll")                                                         \
    for (int j = 0; j < 8; ++j) { v0[j]=f2bf(vreg[j]); v1[j]=f2bf(vreg[8+j]); } \
    *(short8*)vwa = v0; *(short8*)vwb = v1;                                   \
  } while (0)

// ---- one KV step: QK^T, mask, online softmax, pack P, PV ----
#define COMPUTE(MCUR)                                                         \
  do {                                                                        \
    f32x16 st0, st1;                                                          \
    _Pragma("unroll")                                                         \
    for (int i = 0; i < 16; ++i) { st0[i] = 0.f; st1[i] = 0.f; }              \
    _Pragma("unroll")                                                         \
    for (int s = 0; s < 4; ++s) {                                             \
      short8 kf = *(const short8*)(krd + ((32*s + hh) ^ swz));                \
      st0 = MFMA32(kf, qf[s], st0, 0, 0, 0);                                  \
      short8 kg = *(const short8*)(krd + 4096 + ((32*s + hh) ^ swz));         \
      st1 = MFMA32(kg, qf[s], st1, 0, 0, 0);                                  \
    }                                                                         \
    float p0[16], p1[16];                                                     \
    _Pragma("unroll")                                                         \
    for (int g = 0; g < 4; ++g) {                                             \
      int4 m0 = MCUR[g]; int4 m1 = MCUR[4 + g];                               \
      p0[4*g+0] = m0.x ? NEGF : st0[4*g+0];                                   \
      p0[4*g+1] = m0.y ? NEGF : st0[4*g+1];                                   \
      p0[4*g+2] = m0.z ? NEGF : st0[4*g+2];                                   \
      p0[4*g+3] = m0.w ? NEGF : st0[4*g+3];                                   \
      p1[4*g+0] = m1.x ? NEGF : st1[4*g+0];                                   \
      p1[4*g+1] = m1.y ? NEGF : st1[4*g+1];                                   \
      p1[4*g+2] = m1.z ? NEGF : st1[4*g+2];                                   \
      p1[4*g+3] = m1.w ? NEGF : st1[4*g+3];                                   \
    }                                                                         \
    float mx8[8];                                                             \
    _Pragma("unroll")                                                         \
    for (int i = 0; i < 8; ++i)                                               \
      mx8[i] = fmaxf(fmaxf(p0[i], p0[i+8]), fmaxf(p1[i], p1[i+8]));           \
    float mx = fmaxf(fmaxf(fmaxf(mx8[0],mx8[1]), fmaxf(mx8[2],mx8[3])),       \
                     fmaxf(fmaxf(mx8[4],mx8[5]), fmaxf(mx8[6],mx8[7])));      \
    mx = fmaxf(mx, __shfl_xor(mx, 32));                                       \
    if (!__all(mx <= mrun)) {                                                 \
      float mnew  = fmaxf(mrun, mx);                                          \
      float alpha = EXP2(mrun - mnew);                                        \
      lrun *= alpha;                                                          \
      _Pragma("unroll")                                                       \
      for (int i = 0; i < 16; ++i) { ot0[i] *= alpha; ot1[i] *= alpha; }      \
      mrun = mnew;                                                            \
    }                                                                         \
    _Pragma("unroll")                                                         \
    for (int i = 0; i < 16; ++i) {                                            \
      p0[i] = EXP2(p0[i] - mrun);                                             \
      p1[i] = EXP2(p1[i] - mrun);                                             \
    }                                                                         \
    float s8[8];                                                              \
    _Pragma("unroll")                                                         \
    for (int i = 0; i < 8; ++i) s8[i] = (p0[i]+p0[i+8]) + (p1[i]+p1[i+8]);    \
    float lsum = ((s8[0]+s8[1]) + (s8[2]+s8[3])) +                            \
                 ((s8[4]+s8[5]) + (s8[6]+s8[7]));                             \
    lsum += __shfl_xor(lsum, 32);                                             \
    lrun += lsum;                                                             \
    union U8 { unsigned u[4]; short8 s; } f0, f1, f2, f3;                     \
    {                                                                         \
      unsigned x0 = pkbf(p0[0],p0[1]),   x1 = pkbf(p0[2],p0[3]);              \
      unsigned y0 = pkbf(p0[4],p0[5]),   y1 = pkbf(p0[6],p0[7]);              \
      unsigned a0 = pkbf(p0[8],p0[9]),   a1 = pkbf(p0[10],p0[11]);            \
      unsigned b0 = pkbf(p0[12],p0[13]), b1 = pkbf(p0[14],p0[15]);            \
      unsigned sx0 = __shfl_xor(x0,32), sx1 = __shfl_xor(x1,32);              \
      unsigned sy0 = __shfl_xor(y0,32), sy1 = __shfl_xor(y1,32);              \
      unsigned sa0 = __shfl_xor(a0,32), sa1 = __shfl_xor(a1,32);              \
      unsigned sb0 = __shfl_xor(b0,32), sb1 = __shfl_xor(b1,32);              \
      f0.u[0] = h ? sy0 : x0;  f0.u[1] = h ? sy1 : x1;                        \
      f0.u[2] = h ? y0 : sx0;  f0.u[3] = h ? y1 : sx1;                        \
      f1.u[0] = h ? sb0 : a0;  f1.u[1] = h ? sb1 : a1;                        \
      f1.u[2] = h ? b0 : sa0;  f1.u[3] = h ? b1 : sa1;                        \
    }                                                                         \
    {                                                                         \
      unsigned x0 = pkbf(p1[0],p1[1]),   x1 = pkbf(p1[2],p1[3]);              \
      unsigned y0 = pkbf(p1[4],p1[5]),   y1 = pkbf(p1[6],p1[7]);              \
      unsigned a0 = pkbf(p1[8],p1[9]),   a1 = pkbf(p1[10],p1[11]);            \
      unsigned b0 = pkbf(p1[12],p1[13]), b1 = pkbf(p1[14],p1[15]);            \
      unsigned sx0 = __shfl_xor(x0,32), sx1 = __shfl_xor(x1,32);              \
      unsigned sy0 = __shfl_xor(y0,32), sy1 = __shfl_xor(y1,32);              \
      unsigned sa0 = __shfl_xor(a0,32), sa1 = __shfl_xor(a1,32);              \
      unsigned sb0 = __shfl_xor(b0,32), sb1 = __shfl_xor(b1,32);              \
      f2.u[0] = h ? sy0 : x0;  f2.u[1] = h ? sy1 : x1;                        \
      f2.u[2] = h ? y0 : sx0;  f2.u[3] = h ? y1 : sx1;                        \
      f3.u[0] = h ? sb0 : a0;  f3.u[1] = h ? sb1 : a1;                        \
      f3.u[2] = h ? b0 : sa0;  f3.u[3] = h ? b1 : sa1;                        \
    }                                                                         \
    _Pragma("unroll")                                                         \
    for (int s = 0; s < 4; ++s) {                                             \
      short8 pf = (s==0) ? f0.s : (s==1) ? f1.s : (s==2) ? f2.s : f3.s;       \
      short8 va = *(const short8*)(vrd + ((32*s + hh) ^ swz));                \
      ot0 = MFMA32(va, pf, ot0, 0, 0, 0);                                     \
      short8 vb = *(const short8*)(vrd + 4096 + ((32*s + hh) ^ swz));         \
      ot1 = MFMA32(vb, pf, ot1, 0, 0, 0);                                     \
    }                                                                         \
  } while (0)

__launch_bounds__(256, 1)
__global__ void attn_fused(const float* __restrict__ Qg,
                           const float* __restrict__ Kg,
                           const float* __restrict__ Vg,
                           const int*   __restrict__ Mg,
                           float* __restrict__ Og) {
  __shared__ short8 lds8[1024];            // 16 KiB: K [0,8K), V^T [8K,16K)
  char* ldsb = (char*)lds8;

  const int tid  = threadIdx.x;
  const int lane = tid & 63;
  const int w    = tid >> 6;               // wave 0..3
  const int l31  = lane & 31;
  const int h    = lane >> 5;
  const int hh   = h << 4;                 // 16*h (byte offset of half's k-slice)
  const int swz  = (l31 & 7) << 4;         // XOR swizzle key for reads
  const int b    = blockIdx.y;
  const int qb   = blockIdx.x * QBLK;
  const int q    = qb + w * 32 + l31;      // this lane's q row

  // ---- Q fragments (B-operand), scale log2(e)/sqrt(D) folded in ----
  const float qscale = 0.18033688011112042f;   // log2(e)/8
  const float* qp = Qg + ((size_t)(b * Qn + q)) * Dn + 8 * h;
  short8 qf[4];
#pragma unroll
  for (int s = 0; s < 4; ++s) {
    float4 a = *(const float4*)(qp + 16 * s);
    float4 c = *(const float4*)(qp + 16 * s + 4);
    short8 f;
    f[0]=f2bf(a.x*qscale); f[1]=f2bf(a.y*qscale); f[2]=f2bf(a.z*qscale); f[3]=f2bf(a.w*qscale);
    f[4]=f2bf(c.x*qscale); f[5]=f2bf(c.y*qscale); f[6]=f2bf(c.z*qscale); f[7]=f2bf(c.w*qscale);
    qf[s] = f;
  }

  // ---- staging assignments (whole block cooperates, tiles shared by 4 waves) ----
  const int krow = tid >> 3, kc8 = tid & 7;        // K: row, 8-col chunk
  const float* kp = Kg + ((size_t)b * Kseq + krow) * Dn + kc8 * 8;
  const int vd = tid >> 2, vkc = (tid & 3) << 4;   // V^T: d-row, 16-kv chunk
  const float* vp = Vg + ((size_t)b * Kseq + vkc) * Dn + vd;
  char* kwa = ldsb + krow * 128 + ((kc8 * 16) ^ ((krow & 7) << 4));
  char* kwb = kwa + 32 * 128;                      // (krow+32)&7 == krow&7
  char* vwa = ldsb + 8192 + vd * 128 + (((vkc * 2)     ) ^ ((vd & 7) << 4));
  char* vwb = ldsb + 8192 + vd * 128 + (((vkc * 2) + 16) ^ ((vd & 7) << 4));
  const char* krd = ldsb + l31 * 128;
  const char* vrd = ldsb + 8192 + l31 * 128;

  // mask: lane reads its own q-row, kv runs of 4 ints (D-fragment order)
  const int4* mp = (const int4*)(Mg + ((size_t)(b * Qn + q)) * Kseq) + h;

  // ---- state ----
  f32x16 ot0, ot1;
#pragma unroll
  for (int i = 0; i < 16; ++i) { ot0[i] = 0.f; ot1[i] = 0.f; }
  float mrun = NEGF, lrun = 0.f;

  float4 ka0, ka1, kb0, kb1;
  float  vreg[16];
  int4   ma[8], mb[8];

  // ---- prologue: tile 0 + mask step 0 ----
  PREFETCH(ma);
  WRITELDS();
  __syncthreads();

#pragma unroll 1
  for (int kt = 0; kt < 32; kt += 2) {
    // even step kt: compute(ma), prefetch tile kt+1 (always exists)
    PREFETCH(mb);
    COMPUTE(ma);
    __syncthreads();
    WRITELDS();
    __syncthreads();
    // odd step kt+1: compute(mb), prefetch tile kt+2 if it exists
    if (kt + 1 < 31) { PREFETCH(ma); }
    COMPUTE(mb);
    __syncthreads();
    if (kt + 1 < 31) { WRITELDS(); }
    __syncthreads();
  }

  // ---- epilogue: normalize, store (lane q; d = (r&3)+8*(r>>2)+4h [+32]) ----
  float inv = 1.0f / lrun;
  float* op = Og + ((size_t)(b * Qn + q)) * Dn;
#pragma unroll
  for (int g = 0; g < 4; ++g) {
    float4 o;
    o.x = ot0[4*g+0] * inv; o.y = ot0[4*g+1] * inv;
    o.z = ot0[4*g+2] * inv; o.w = ot0[4*g+3] * inv;
    *(float4*)(op + 8*g + 4*h) = o;
    o.x = ot1[4*g+0] * inv; o.y = ot1[4*g+1] * inv;
    o.z = ot1[4*g+2] * inv; o.w = ot1[4*g+3] * inv;
    *(float4*)(op + 32 + 8*g + 4*h) = o;
  }
}

extern "C" void kernel_launch(void* const* d_in, const int* in_sizes, int n_in,
                              void* d_out, int out_size, void* d_ws, size_t ws_size,
                              hipStream_t stream) {
  const float* Q = (const float*)d_in[0];
  const float* K = (const float*)d_in[1];
  const float* V = (const float*)d_in[2];
  const int*   M = (const int*)d_in[3];
  float* O = (float*)d_out;
  dim3 grid(Qn / QBLK, Bn);   // (16, 16)
  attn_fused<<<grid, dim3(256), 0, stream>>>(Q, K, V, M, O);
}

// Round 5
// 409.194 us; speedup vs baseline: 1.0099x; 1.0099x over previous
//
#include <hip/hip_runtime.h>

// DotProductAttention B=16, Q=K=2048, D=64, fp32 io, mask int32 (nonzero -> -1e30).
// Flash attention, swapped-QK^T (S^T = K.Q^T): softmax + O^T accum are per-lane-q.
// 512-thread blocks, KV-split: waves 0-3 even KV tiles, waves 4-7 odd tiles,
// merged via LDS at the end. Coalesced K/V staging, bitmask-compressed mask,
// no unions (bit_cast), in-place softmax on MFMA accumulators.

#define Bn   16
#define Qn   2048
#define Kseq 2048
#define Dn   64
#define QBLK 128
#define NEGF (-1e30f)

typedef __attribute__((ext_vector_type(4)))  short short4v;
typedef __attribute__((ext_vector_type(8)))  short short8;
typedef __attribute__((ext_vector_type(4)))  unsigned uint4v;
typedef __attribute__((ext_vector_type(16))) float f32x16;

static __device__ __forceinline__ short f2bf(float x) {
  union { float f; unsigned u; } un; un.f = x;          // scalar union: SROA-safe
  unsigned r = un.u + 0x7FFFu + ((un.u >> 16) & 1u);    // RNE
  return (short)(r >> 16);
}
static __device__ __forceinline__ unsigned pkbf(float lo, float hi) {
  unsigned r;
  asm("v_cvt_pk_bf16_f32 %0, %1, %2" : "=v"(r) : "v"(lo), "v"(hi));
  return r;
}
#if __has_builtin(__builtin_amdgcn_exp2f)
#define EXP2 __builtin_amdgcn_exp2f
#else
#define EXP2 exp2f
#endif
#define MFMA32 __builtin_amdgcn_mfma_f32_32x32x16_bf16

// ---- per-pair prefetch: K 4xfloat4 chunk-linear, V 8xfloat2 row-pairs, mask 8xint4 ----
#define PREF_KV()                                                             \
  do {                                                                        \
    kst[0] = kp4[co0]; kst[1] = kp4[co1];                                     \
    kst[2] = kp4[co2]; kst[3] = kp4[co3];                                     \
    _Pragma("unroll")                                                         \
    for (int j2 = 0; j2 < 8; ++j2) vst[j2] = *(const float2*)(vp + j2 * 64);  \
    kp4 += 2048; vp += 8192;                                                  \
  } while (0)

#define PREF_M()                                                              \
  do {                                                                        \
    _Pragma("unroll")                                                         \
    for (int g = 0; g < 8; ++g) ma[g] = mp[2 * g];                            \
    mp += 32;                                                                 \
  } while (0)

#define WRITELDS()                                                            \
  do {                                                                        \
    _Pragma("unroll")                                                         \
    for (int i = 0; i < 4; ++i) {                                             \
      float4 a = kst[i]; short4v t;                                           \
      t[0] = f2bf(a.x); t[1] = f2bf(a.y); t[2] = f2bf(a.z); t[3] = f2bf(a.w); \
      *(short4v*)kdst[i] = t;                                                 \
    }                                                                         \
    short8 v0, v1;                                                            \
    _Pragma("unroll")                                                         \
    for (int j2 = 0; j2 < 8; ++j2) { v0[j2] = f2bf(vst[j2].x); v1[j2] = f2bf(vst[j2].y); } \
    *(short8*)vdst0 = v0; *(short8*)vdst1 = v1;                               \
  } while (0)

static __device__ __forceinline__ unsigned compress_mask(const int4* ma) {
  unsigned bits = 0;
#pragma unroll
  for (int g = 0; g < 8; ++g) {
    int4 m = ma[g];
    const int sh = ((g & 4) << 2) + ((g & 3) << 2);   // g<4 -> 4g (st0), g>=4 -> 16+4(g-4) (st1)
    unsigned bsel = (m.x != 0 ? 1u : 0u) | (m.y != 0 ? 2u : 0u) |
                    (m.z != 0 ? 4u : 0u) | (m.w != 0 ? 8u : 0u);
    bits |= bsel << sh;
  }
  return bits;
}

// ---- one KV tile: QK^T, mask, online softmax (in place), pack P, PV ----
#define COMPUTE()                                                             \
  do {                                                                        \
    f32x16 st0, st1;                                                          \
    _Pragma("unroll")                                                         \
    for (int i = 0; i < 16; ++i) { st0[i] = 0.f; st1[i] = 0.f; }              \
    _Pragma("unroll")                                                         \
    for (int s = 0; s < 4; ++s) {                                             \
      short8 kf = *(const short8*)(krd + ((32 * s + hh) ^ swz));              \
      st0 = MFMA32(kf, qf[s], st0, 0, 0, 0);                                  \
      short8 kg = *(const short8*)(krd + 4096 + ((32 * s + hh) ^ swz));       \
      st1 = MFMA32(kg, qf[s], st1, 0, 0, 0);                                  \
    }                                                                         \
    _Pragma("unroll")                                                         \
    for (int i = 0; i < 16; ++i) {                                            \
      st0[i] = (bits & (1u << i))       ? NEGF : st0[i];                      \
      st1[i] = (bits & (0x10000u << i)) ? NEGF : st1[i];                      \
    }                                                                         \
    float mx8[8];                                                             \
    _Pragma("unroll")                                                         \
    for (int i = 0; i < 8; ++i)                                               \
      mx8[i] = fmaxf(fmaxf(st0[i], st0[i+8]), fmaxf(st1[i], st1[i+8]));       \
    float mx = fmaxf(fmaxf(fmaxf(mx8[0],mx8[1]), fmaxf(mx8[2],mx8[3])),       \
                     fmaxf(fmaxf(mx8[4],mx8[5]), fmaxf(mx8[6],mx8[7])));      \
    mx = fmaxf(mx, __shfl_xor(mx, 32));                                       \
    if (!__all(mx <= mrun)) {                                                 \
      float mnew  = fmaxf(mrun, mx);                                          \
      float alpha = EXP2(mrun - mnew);                                        \
      lrun *= alpha;                                                          \
      _Pragma("unroll")                                                       \
      for (int i = 0; i < 16; ++i) { ot0[i] *= alpha; ot1[i] *= alpha; }      \
      mrun = mnew;                                                            \
    }                                                                         \
    _Pragma("unroll")                                                         \
    for (int i = 0; i < 16; ++i) {                                            \
      st0[i] = EXP2(st0[i] - mrun);                                           \
      st1[i] = EXP2(st1[i] - mrun);                                           \
    }                                                                         \
    float s8[8];                                                              \
    _Pragma("unroll")                                                         \
    for (int i = 0; i < 8; ++i) s8[i] = (st0[i]+st0[i+8]) + (st1[i]+st1[i+8]);\
    float lsum = ((s8[0]+s8[1]) + (s8[2]+s8[3])) +                            \
                 ((s8[4]+s8[5]) + (s8[6]+s8[7]));                             \
    lsum += __shfl_xor(lsum, 32);                                             \
    lrun += lsum;                                                             \
    short8 f0, f1, f2, f3;                                                    \
    {                                                                         \
      unsigned x0 = pkbf(st0[0],st0[1]),   x1 = pkbf(st0[2],st0[3]);          \
      unsigned y0 = pkbf(st0[4],st0[5]),   y1 = pkbf(st0[6],st0[7]);          \
      unsigned a0 = pkbf(st0[8],st0[9]),   a1 = pkbf(st0[10],st0[11]);        \
      unsigned b0 = pkbf(st0[12],st0[13]), b1 = pkbf(st0[14],st0[15]);        \
      unsigned sx0 = __shfl_xor(x0,32), sx1 = __shfl_xor(x1,32);              \
      unsigned sy0 = __shfl_xor(y0,32), sy1 = __shfl_xor(y1,32);              \
      unsigned sa0 = __shfl_xor(a0,32), sa1 = __shfl_xor(a1,32);              \
      unsigned sb0 = __shfl_xor(b0,32), sb1 = __shfl_xor(b1,32);              \
      uint4v u0 = { h ? sy0 : x0, h ? sy1 : x1, h ? y0 : sx0, h ? y1 : sx1 }; \
      uint4v u1 = { h ? sb0 : a0, h ? sb1 : a1, h ? b0 : sa0, h ? b1 : sa1 }; \
      f0 = __builtin_bit_cast(short8, u0);                                    \
      f1 = __builtin_bit_cast(short8, u1);                                    \
    }                                                                         \
    {                                                                         \
      unsigned x0 = pkbf(st1[0],st1[1]),   x1 = pkbf(st1[2],st1[3]);          \
      unsigned y0 = pkbf(st1[4],st1[5]),   y1 = pkbf(st1[6],st1[7]);          \
      unsigned a0 = pkbf(st1[8],st1[9]),   a1 = pkbf(st1[10],st1[11]);        \
      unsigned b0 = pkbf(st1[12],st1[13]), b1 = pkbf(st1[14],st1[15]);        \
      unsigned sx0 = __shfl_xor(x0,32), sx1 = __shfl_xor(x1,32);              \
      unsigned sy0 = __shfl_xor(y0,32), sy1 = __shfl_xor(y1,32);              \
      unsigned sa0 = __shfl_xor(a0,32), sa1 = __shfl_xor(a1,32);              \
      unsigned sb0 = __shfl_xor(b0,32), sb1 = __shfl_xor(b1,32);              \
      uint4v u2 = { h ? sy0 : x0, h ? sy1 : x1, h ? y0 : sx0, h ? y1 : sx1 }; \
      uint4v u3 = { h ? sb0 : a0, h ? sb1 : a1, h ? b0 : sa0, h ? b1 : sa1 }; \
      f2 = __builtin_bit_cast(short8, u2);                                    \
      f3 = __builtin_bit_cast(short8, u3);                                    \
    }                                                                         \
    _Pragma("unroll")                                                         \
    for (int s = 0; s < 4; ++s) {                                             \
      short8 pf = (s==0) ? f0 : (s==1) ? f1 : (s==2) ? f2 : f3;               \
      short8 va = *(const short8*)(vrd + ((32 * s + hh) ^ swz));              \
      ot0 = MFMA32(va, pf, ot0, 0, 0, 0);                                     \
      short8 vb = *(const short8*)(vrd + 4096 + ((32 * s + hh) ^ swz));       \
      ot1 = MFMA32(vb, pf, ot1, 0, 0, 0);                                     \
    }                                                                         \
  } while (0)

__launch_bounds__(512, 2)
__global__ void attn_fused(const float* __restrict__ Qg,
                           const float* __restrict__ Kg,
                           const float* __restrict__ Vg,
                           const int*   __restrict__ Mg,
                           float* __restrict__ Og) {
  __shared__ char ldsb[32768];   // K pair [0,16K): tiles A,B; V^T pair [16K,32K)

  const int tid  = threadIdx.x;
  const int lane = tid & 63;
  const int w    = tid >> 6;     // wave 0..7
  const int wq   = w & 3;        // q-subtile
  const int grp  = w >> 2;       // 0: even tiles, 1: odd tiles
  const int l31  = lane & 31;
  const int h    = lane >> 5;
  const int hh   = h << 4;
  const int swz  = (l31 & 7) << 4;
  const int b    = blockIdx.y;
  const int qb   = blockIdx.x * QBLK;
  const int q    = qb + wq * 32 + l31;

  // ---- Q fragments (B-operand), log2(e)/sqrt(D) folded ----
  const float qscale = 0.18033688011112042f;   // log2(e)/8
  const float* qp = Qg + ((size_t)(b * Qn + q)) * Dn + 8 * h;
  short8 qf[4];
#pragma unroll
  for (int s = 0; s < 4; ++s) {
    float4 a = *(const float4*)(qp + 16 * s);
    float4 c = *(const float4*)(qp + 16 * s + 4);
    short8 f;
    f[0]=f2bf(a.x*qscale); f[1]=f2bf(a.y*qscale); f[2]=f2bf(a.z*qscale); f[3]=f2bf(a.w*qscale);
    f[4]=f2bf(c.x*qscale); f[5]=f2bf(c.y*qscale); f[6]=f2bf(c.z*qscale); f[7]=f2bf(c.w*qscale);
    qf[s] = f;
  }

  // ---- K staging: chunk-linear over the 128-row pair (fully coalesced) ----
  const float4* kp4 = (const float4*)(Kg + (size_t)b * Kseq * Dn);
  const int co0 = tid, co1 = tid + 512, co2 = tid + 1024, co3 = tid + 1536;
  char* kdst[4];
#pragma unroll
  for (int i = 0; i < 4; ++i) {
    int c = tid + 512 * i;
    int row = c >> 4, col16 = c & 15;        // row in pair (0..127), 16B col chunk
    int tile = row >> 6, r = row & 63;
    kdst[i] = ldsb + tile * 8192 + r * 128 +
              (((col16 >> 1) << 4) ^ ((r & 7) << 4)) + ((col16 & 1) << 3);
  }

  // ---- V staging: row-pair coalesced float2, transposed into V^T LDS ----
  const int uu = tid & 255, tileV = tid >> 8;
  const int d0 = (uu & 31) * 2, kv8 = (uu >> 5) * 8;
  const float* vp = Vg + ((size_t)b * Kseq + tileV * 64 + kv8) * Dn + d0;
  char* vdst0 = ldsb + 16384 + tileV * 8192 + d0 * 128 + ((kv8 * 2) ^ ((d0 & 7) << 4));
  char* vdst1 = ldsb + 16384 + tileV * 8192 + (d0 + 1) * 128 + ((kv8 * 2) ^ (((d0 + 1) & 7) << 4));

  // ---- mask: own q-row, own group's tile of each pair ----
  const int4* mp = (const int4*)(Mg + ((size_t)(b * Qn + q)) * Kseq) + 16 * grp + h;

  // ---- LDS read bases (group-selected tile) ----
  const char* krd = ldsb + grp * 8192 + l31 * 128;
  const char* vrd = ldsb + 16384 + grp * 8192 + l31 * 128;

  // ---- state ----
  f32x16 ot0, ot1;
#pragma unroll
  for (int i = 0; i < 16; ++i) { ot0[i] = 0.f; ot1[i] = 0.f; }
  float mrun = NEGF, lrun = 0.f;

  float4 kst[4];
  float2 vst[8];
  int4   ma[8];
  unsigned bits;

  // ---- prologue: pair 0 ----
  PREF_KV();
  PREF_M();
  WRITELDS();
  bits = compress_mask(ma);
  __syncthreads();

#pragma unroll 1
  for (int j = 0; j < 16; ++j) {
    if (j < 15) { PREF_KV(); PREF_M(); }    // pair j+1 -> regs (in flight)
    COMPUTE();                              // pair j (own tile), uses bits
    if (j < 15) {
      bits = compress_mask(ma);             // pair j+1 mask -> 32 bits
      __syncthreads();                      // all waves done reading pair j
      WRITELDS();                           // pair j+1 -> LDS
      __syncthreads();                      // pair j+1 visible
    }
  }

  // all waves done with their last COMPUTE (LDS reads) before the merge
  // buffers below overwrite the K/V^T regions.  (RACE fix vs round 3.)
  __syncthreads();

  // ---- merge the two KV-halves (wave w <- wave w+4), normalize, store ----
  float* lm = (float*)ldsb;                 // [4][64] running max (group B)
  float* ll = lm + 256;                     // [4][64] running sum
  float* lo = ll + 256;                     // [4][64][stride 20] O^T halves
  const int s4 = wq * 64 + lane;
  if (grp == 1) {
    lm[s4] = mrun; ll[s4] = lrun;
#pragma unroll
    for (int i = 0; i < 16; ++i) lo[s4 * 20 + i] = ot0[i];
  }
  __syncthreads();
  float aA = 1.f, aB = 0.f;
  if (grp == 0) {
    float mB = lm[s4], lB = ll[s4];
    float ms = fmaxf(mrun, mB);
    aA = EXP2(mrun - ms); aB = EXP2(mB - ms);
    lrun = lrun * aA + lB * aB;
#pragma unroll
    for (int i = 0; i < 16; ++i) ot0[i] = ot0[i] * aA + lo[s4 * 20 + i] * aB;
  }
  __syncthreads();
  if (grp == 1) {
#pragma unroll
    for (int i = 0; i < 16; ++i) lo[s4 * 20 + i] = ot1[i];
  }
  __syncthreads();
  if (grp == 0) {
#pragma unroll
    for (int i = 0; i < 16; ++i) ot1[i] = ot1[i] * aA + lo[s4 * 20 + i] * aB;
    float inv = 1.0f / lrun;
    float* op = Og + ((size_t)(b * Qn + q)) * Dn;
#pragma unroll
    for (int g = 0; g < 4; ++g) {
      float4 o;
      o.x = ot0[4*g+0] * inv; o.y = ot0[4*g+1] * inv;
      o.z = ot0[4*g+2] * inv; o.w = ot0[4*g+3] * inv;
      *(float4*)(op + 8*g + 4*h) = o;
      o.x = ot1[4*g+0] * inv; o.y = ot1[4*g+1] * inv;
      o.z = ot1[4*g+2] * inv; o.w = ot1[4*g+3] * inv;
      *(float4*)(op + 32 + 8*g + 4*h) = o;
    }
  }
}

extern "C" void kernel_launch(void* const* d_in, const int* in_sizes, int n_in,
                              void* d_out, int out_size, void* d_ws, size_t ws_size,
                              hipStream_t stream) {
  const float* Q = (const float*)d_in[0];
  const float* K = (const float*)d_in[1];
  const float* V = (const float*)d_in[2];
  const int*   M = (const int*)d_in[3];
  float* O = (float*)d_out;
  dim3 grid(Qn / QBLK, Bn);   // (16, 16)
  attn_fused<<<grid, dim3(512), 0, stream>>>(Q, K, V, M, O);
}

// Round 9
// 380.390 us; speedup vs baseline: 1.0864x; 1.0757x over previous
//
#include <hip/hip_runtime.h>

// DotProductAttention B=16, Q=K=2048, D=64, fp32 io, mask int32 (nonzero -> -1e30).
// Flash attention, swapped-QK^T (S^T = K.Q^T): softmax + O^T accum per-lane-q.
// R6 change (single variable vs R5): mask path rebuilt. Coalesced 512B-run
// loads (8 lanes per row), in-register 16:1 bit-compression, LDS transpose
// (2KB), per-lane uint2 ds_read. Replaces the 8KB-stride per-lane scatter
// (64 lines / 16B-each per wave-instr) that R2+R5 shared.

#define Bn   16
#define Qn   2048
#define Kseq 2048
#define Dn   64
#define QBLK 128
#define NEGF (-1e30f)

typedef __attribute__((ext_vector_type(4)))  short short4v;
typedef __attribute__((ext_vector_type(8)))  short short8;
typedef __attribute__((ext_vector_type(4)))  unsigned uint4v;
typedef __attribute__((ext_vector_type(16))) float f32x16;

static __device__ __forceinline__ short f2bf(float x) {
  union { float f; unsigned u; } un; un.f = x;          // scalar union: SROA-safe
  unsigned r = un.u + 0x7FFFu + ((un.u >> 16) & 1u);    // RNE
  return (short)(r >> 16);
}
static __device__ __forceinline__ unsigned pkbf(float lo, float hi) {
  unsigned r;
  asm("v_cvt_pk_bf16_f32 %0, %1, %2" : "=v"(r) : "v"(lo), "v"(hi));
  return r;
}
#if __has_builtin(__builtin_amdgcn_exp2f)
#define EXP2 __builtin_amdgcn_exp2f
#else
#define EXP2 exp2f
#endif
#define MFMA32 __builtin_amdgcn_mfma_f32_32x32x16_bf16

// ---- prefetch next pair: K 4xfloat4 chunk-linear, V 8xfloat2 row-pairs,
//      mask 2 passes x 4 consecutive int4 (512B run per 8-lane row group) ----
#define PREF_KV()                                                             \
  do {                                                                        \
    kst[0] = kp4[co0]; kst[1] = kp4[co1];                                     \
    kst[2] = kp4[co2]; kst[3] = kp4[co3];                                     \
    _Pragma("unroll")                                                         \
    for (int j2 = 0; j2 < 8; ++j2) vst[j2] = *(const float2*)(vp + j2 * 64);  \
    kp4 += 2048; vp += 8192;                                                  \
  } while (0)

#define PREF_M()                                                              \
  do {                                                                        \
    _Pragma("unroll")                                                         \
    for (int p = 0; p < 2; ++p)                                               \
      _Pragma("unroll")                                                       \
      for (int jj = 0; jj < 4; ++jj)                                          \
        mld[p * 4 + jj] = mpp[p * 32768 + jj];                                \
    mpp += 32;                                                                \
  } while (0)

// K/V -> LDS (bf16, swizzled) then mask compress -> LDS transpose buffer
#define WRITELDS()                                                            \
  do {                                                                        \
    _Pragma("unroll")                                                         \
    for (int i = 0; i < 4; ++i) {                                             \
      float4 a = kst[i]; short4v t;                                           \
      t[0] = f2bf(a.x); t[1] = f2bf(a.y); t[2] = f2bf(a.z); t[3] = f2bf(a.w); \
      *(short4v*)kdst[i] = t;                                                 \
    }                                                                         \
    short8 v0, v1;                                                            \
    _Pragma("unroll")                                                         \
    for (int j2 = 0; j2 < 8; ++j2) { v0[j2] = f2bf(vst[j2].x); v1[j2] = f2bf(vst[j2].y); } \
    *(short8*)vdst0 = v0; *(short8*)vdst1 = v1;                               \
    _Pragma("unroll")                                                         \
    for (int p = 0; p < 2; ++p) {                                             \
      unsigned v = 0;                                                         \
      _Pragma("unroll")                                                       \
      for (int jj = 0; jj < 4; ++jj) {                                        \
        int4 m = mld[p * 4 + jj];                                             \
        v |= (m.x != 0 ? 1u : 0u) << (jj * 4);                                \
        v |= (m.y != 0 ? 2u : 0u) << (jj * 4);                                \
        v |= (m.z != 0 ? 4u : 0u) << (jj * 4);                                \
        v |= (m.w != 0 ? 8u : 0u) << (jj * 4);                                \
      }                                                                       \
      mwr[p * 512] = (unsigned short)v;                                       \
    }                                                                         \
  } while (0)

// ---- one KV tile: mask bits from LDS, QK^T, mask, online softmax, pack, PV ----
#define COMPUTE()                                                             \
  do {                                                                        \
    const uint2 mb = *(const uint2*)mrd;                                      \
    const unsigned xh = mb.x >> (4 * h);                                      \
    const unsigned yh = mb.y >> (4 * h);                                      \
    f32x16 st0, st1;                                                          \
    _Pragma("unroll")                                                         \
    for (int i = 0; i < 16; ++i) { st0[i] = 0.f; st1[i] = 0.f; }              \
    _Pragma("unroll")                                                         \
    for (int s = 0; s < 4; ++s) {                                             \
      short8 kf = *(const short8*)(krd + ((32 * s + hh) ^ swz));              \
      st0 = MFMA32(kf, qf[s], st0, 0, 0, 0);                                  \
      short8 kg = *(const short8*)(krd + 4096 + ((32 * s + hh) ^ swz));       \
      st1 = MFMA32(kg, qf[s], st1, 0, 0, 0);                                  \
    }                                                                         \
    _Pragma("unroll")                                                         \
    for (int i = 0; i < 16; ++i) {                                            \
      const int bi = 8 * (i >> 2) + (i & 3);                                  \
      st0[i] = ((xh >> bi) & 1u) ? NEGF : st0[i];                             \
      st1[i] = ((yh >> bi) & 1u) ? NEGF : st1[i];                             \
    }                                                                         \
    float mx8[8];                                                             \
    _Pragma("unroll")                                                         \
    for (int i = 0; i < 8; ++i)                                               \
      mx8[i] = fmaxf(fmaxf(st0[i], st0[i+8]), fmaxf(st1[i], st1[i+8]));       \
    float mx = fmaxf(fmaxf(fmaxf(mx8[0],mx8[1]), fmaxf(mx8[2],mx8[3])),       \
                     fmaxf(fmaxf(mx8[4],mx8[5]), fmaxf(mx8[6],mx8[7])));      \
    mx = fmaxf(mx, __shfl_xor(mx, 32));                                       \
    if (!__all(mx <= mrun)) {                                                 \
      float mnew  = fmaxf(mrun, mx);                                          \
      float alpha = EXP2(mrun - mnew);                                        \
      lrun *= alpha;                                                          \
      _Pragma("unroll")                                                       \
      for (int i = 0; i < 16; ++i) { ot0[i] *= alpha; ot1[i] *= alpha; }      \
      mrun = mnew;                                                            \
    }                                                                         \
    _Pragma("unroll")                                                         \
    for (int i = 0; i < 16; ++i) {                                            \
      st0[i] = EXP2(st0[i] - mrun);                                           \
      st1[i] = EXP2(st1[i] - mrun);                                           \
    }                                                                         \
    float s8[8];                                                              \
    _Pragma("unroll")                                                         \
    for (int i = 0; i < 8; ++i) s8[i] = (st0[i]+st0[i+8]) + (st1[i]+st1[i+8]);\
    float lsum = ((s8[0]+s8[1]) + (s8[2]+s8[3])) +                            \
                 ((s8[4]+s8[5]) + (s8[6]+s8[7]));                             \
    lsum += __shfl_xor(lsum, 32);                                             \
    lrun += lsum;                                                             \
    short8 f0, f1, f2, f3;                                                    \
    {                                                                         \
      unsigned x0 = pkbf(st0[0],st0[1]),   x1 = pkbf(st0[2],st0[3]);          \
      unsigned y0 = pkbf(st0[4],st0[5]),   y1 = pkbf(st0[6],st0[7]);          \
      unsigned a0 = pkbf(st0[8],st0[9]),   a1 = pkbf(st0[10],st0[11]);        \
      unsigned b0 = pkbf(st0[12],st0[13]), b1 = pkbf(st0[14],st0[15]);        \
      unsigned sx0 = __shfl_xor(x0,32), sx1 = __shfl_xor(x1,32);              \
      unsigned sy0 = __shfl_xor(y0,32), sy1 = __shfl_xor(y1,32);              \
      unsigned sa0 = __shfl_xor(a0,32), sa1 = __shfl_xor(a1,32);              \
      unsigned sb0 = __shfl_xor(b0,32), sb1 = __shfl_xor(b1,32);              \
      uint4v u0 = { h ? sy0 : x0, h ? sy1 : x1, h ? y0 : sx0, h ? y1 : sx1 }; \
      uint4v u1 = { h ? sb0 : a0, h ? sb1 : a1, h ? b0 : sa0, h ? b1 : sa1 }; \
      f0 = __builtin_bit_cast(short8, u0);                                    \
      f1 = __builtin_bit_cast(short8, u1);                                    \
    }                                                                         \
    {                                                                         \
      unsigned x0 = pkbf(st1[0],st1[1]),   x1 = pkbf(st1[2],st1[3]);          \
      unsigned y0 = pkbf(st1[4],st1[5]),   y1 = pkbf(st1[6],st1[7]);          \
      unsigned a0 = pkbf(st1[8],st1[9]),   a1 = pkbf(st1[10],st1[11]);        \
      unsigned b0 = pkbf(st1[12],st1[13]), b1 = pkbf(st1[14],st1[15]);        \
      unsigned sx0 = __shfl_xor(x0,32), sx1 = __shfl_xor(x1,32);              \
      unsigned sy0 = __shfl_xor(y0,32), sy1 = __shfl_xor(y1,32);              \
      unsigned sa0 = __shfl_xor(a0,32), sa1 = __shfl_xor(a1,32);              \
      unsigned sb0 = __shfl_xor(b0,32), sb1 = __shfl_xor(b1,32);              \
      uint4v u2 = { h ? sy0 : x0, h ? sy1 : x1, h ? y0 : sx0, h ? y1 : sx1 }; \
      uint4v u3 = { h ? sb0 : a0, h ? sb1 : a1, h ? b0 : sa0, h ? b1 : sa1 }; \
      f2 = __builtin_bit_cast(short8, u2);                                    \
      f3 = __builtin_bit_cast(short8, u3);                                    \
    }                                                                         \
    _Pragma("unroll")                                                         \
    for (int s = 0; s < 4; ++s) {                                             \
      short8 pf = (s==0) ? f0 : (s==1) ? f1 : (s==2) ? f2 : f3;               \
      short8 va = *(const short8*)(vrd + ((32 * s + hh) ^ swz));              \
      ot0 = MFMA32(va, pf, ot0, 0, 0, 0);                                     \
      short8 vb = *(const short8*)(vrd + 4096 + ((32 * s + hh) ^ swz));       \
      ot1 = MFMA32(vb, pf, ot1, 0, 0, 0);                                     \
    }                                                                         \
  } while (0)

__launch_bounds__(512, 2)
__global__ void attn_fused(const float* __restrict__ Qg,
                           const float* __restrict__ Kg,
                           const float* __restrict__ Vg,
                           const int*   __restrict__ Mg,
                           float* __restrict__ Og) {
  // K pair [0,16K); V^T pair [16K,32K); mask bits [32K,34K)
  __shared__ char ldsb[34816];

  const int tid  = threadIdx.x;
  const int lane = tid & 63;
  const int w    = tid >> 6;     // wave 0..7
  const int wq   = w & 3;        // q-subtile
  const int grp  = w >> 2;       // 0: even tiles, 1: odd tiles
  const int l31  = lane & 31;
  const int h    = lane >> 5;
  const int hh   = h << 4;
  const int swz  = (l31 & 7) << 4;
  const int b    = blockIdx.y;
  const int qb   = blockIdx.x * QBLK;
  const int q    = qb + wq * 32 + l31;

  // ---- Q fragments (B-operand), log2(e)/sqrt(D) folded ----
  const float qscale = 0.18033688011112042f;   // log2(e)/8
  const float* qp = Qg + ((size_t)(b * Qn + q)) * Dn + 8 * h;
  short8 qf[4];
#pragma unroll
  for (int s = 0; s < 4; ++s) {
    float4 a = *(const float4*)(qp + 16 * s);
    float4 c = *(const float4*)(qp + 16 * s + 4);
    short8 f;
    f[0]=f2bf(a.x*qscale); f[1]=f2bf(a.y*qscale); f[2]=f2bf(a.z*qscale); f[3]=f2bf(a.w*qscale);
    f[4]=f2bf(c.x*qscale); f[5]=f2bf(c.y*qscale); f[6]=f2bf(c.z*qscale); f[7]=f2bf(c.w*qscale);
    qf[s] = f;
  }

  // ---- K staging: chunk-linear over the 128-row pair (fully coalesced) ----
  const float4* kp4 = (const float4*)(Kg + (size_t)b * Kseq * Dn);
  const int co0 = tid, co1 = tid + 512, co2 = tid + 1024, co3 = tid + 1536;
  char* kdst[4];
#pragma unroll
  for (int i = 0; i < 4; ++i) {
    int c = tid + 512 * i;
    int row = c >> 4, col16 = c & 15;        // row in pair (0..127), 16B col chunk
    int tile = row >> 6, r = row & 63;
    kdst[i] = ldsb + tile * 8192 + r * 128 +
              (((col16 >> 1) << 4) ^ ((r & 7) << 4)) + ((col16 & 1) << 3);
  }

  // ---- V staging: row-pair coalesced float2, transposed into V^T LDS ----
  const int uu = tid & 255, tileV = tid >> 8;
  const int d0 = (uu & 31) * 2, kv8 = (uu >> 5) * 8;
  const float* vp = Vg + ((size_t)b * Kseq + tileV * 64 + kv8) * Dn + d0;
  char* vdst0 = ldsb + 16384 + tileV * 8192 + d0 * 128 + ((kv8 * 2) ^ ((d0 & 7) << 4));
  char* vdst1 = ldsb + 16384 + tileV * 8192 + (d0 + 1) * 128 + ((kv8 * 2) ^ (((d0 + 1) & 7) << 4));

  // ---- mask staging: 8 lanes cover one row's 512B pair-span (coalesced) ----
  // thread t, pass p: row = p*64 + (t>>3); int4s (t&7)*4 + {0..3} of the pair's
  // 32 int4s.  Compressed 16 ints -> 16 bits -> LDS [128 rows][8 ushorts].
  const int4* mpp = (const int4*)(Mg + ((size_t)(b * Qn + qb + (tid >> 3))) * Kseq)
                    + (tid & 7) * 4;
  unsigned short* mwr = (unsigned short*)(ldsb + 32768) + (tid >> 3) * 8 + (tid & 7);
  const char* mrd = ldsb + 32768 + (wq * 32 + l31) * 16 + grp * 8;

  // ---- LDS read bases (group-selected tile) ----
  const char* krd = ldsb + grp * 8192 + l31 * 128;
  const char* vrd = ldsb + 16384 + grp * 8192 + l31 * 128;

  // ---- state ----
  f32x16 ot0, ot1;
#pragma unroll
  for (int i = 0; i < 16; ++i) { ot0[i] = 0.f; ot1[i] = 0.f; }
  float mrun = NEGF, lrun = 0.f;

  float4 kst[4];
  float2 vst[8];
  int4   mld[8];

  // ---- prologue: pair 0 ----
  PREF_KV();
  PREF_M();
  WRITELDS();
  __syncthreads();

#pragma unroll 1
  for (int j = 0; j < 16; ++j) {
    if (j < 15) { PREF_KV(); PREF_M(); }    // pair j+1 -> regs (in flight)
    COMPUTE();                              // pair j (own tile)
    if (j < 15) {
      __syncthreads();                      // all waves done reading pair j
      WRITELDS();                           // pair j+1 -> LDS (K,V,mask)
      __syncthreads();                      // pair j+1 visible
    }
  }

  // all waves done with their last COMPUTE (LDS reads) before the merge
  // buffers below overwrite the K/V^T regions.
  __syncthreads();

  // ---- merge the two KV-halves (wave w <- wave w+4), normalize, store ----
  float* lm = (float*)ldsb;                 // [4][64] running max (group B)
  float* ll = lm + 256;                     // [4][64] running sum
  float* lo = ll + 256;                     // [4][64][stride 20] O^T halves
  const int s4 = wq * 64 + lane;
  if (grp == 1) {
    lm[s4] = mrun; ll[s4] = lrun;
#pragma unroll
    for (int i = 0; i < 16; ++i) lo[s4 * 20 + i] = ot0[i];
  }
  __syncthreads();
  float aA = 1.f, aB = 0.f;
  if (grp == 0) {
    float mB = lm[s4], lB = ll[s4];
    float ms = fmaxf(mrun, mB);
    aA = EXP2(mrun - ms); aB = EXP2(mB - ms);
    lrun = lrun * aA + lB * aB;
#pragma unroll
    for (int i = 0; i < 16; ++i) ot0[i] = ot0[i] * aA + lo[s4 * 20 + i] * aB;
  }
  __syncthreads();
  if (grp == 1) {
#pragma unroll
    for (int i = 0; i < 16; ++i) lo[s4 * 20 + i] = ot1[i];
  }
  __syncthreads();
  if (grp == 0) {
#pragma unroll
    for (int i = 0; i < 16; ++i) ot1[i] = ot1[i] * aA + lo[s4 * 20 + i] * aB;
    float inv = 1.0f / lrun;
    float* op = Og + ((size_t)(b * Qn + q)) * Dn;
#pragma unroll
    for (int g = 0; g < 4; ++g) {
      float4 o;
      o.x = ot0[4*g+0] * inv; o.y = ot0[4*g+1] * inv;
      o.z = ot0[4*g+2] * inv; o.w = ot0[4*g+3] * inv;
      *(float4*)(op + 8*g + 4*h) = o;
      o.x = ot1[4*g+0] * inv; o.y = ot1[4*g+1] * inv;
      o.z = ot1[4*g+2] * inv; o.w = ot1[4*g+3] * inv;
      *(float4*)(op + 32 + 8*g + 4*h) = o;
    }
  }
}

extern "C" void kernel_launch(void* const* d_in, const int* in_sizes, int n_in,
                              void* d_out, int out_size, void* d_ws, size_t ws_size,
                              hipStream_t stream) {
  const float* Q = (const float*)d_in[0];
  const float* K = (const float*)d_in[1];
  const float* V = (const float*)d_in[2];
  const int*   M = (const int*)d_in[3];
  float* O = (float*)d_out;
  dim3 grid(Qn / QBLK, Bn);   // (16, 16)
  attn_fused<<<grid, dim3(512), 0, stream>>>(Q, K, V, M, O);
}

// Round 11
// 379.209 us; speedup vs baseline: 1.0897x; 1.0031x over previous
//
#include <hip/hip_runtime.h>

// DotProductAttention B=16, Q=K=2048, D=64, fp32 io, mask int32 (nonzero -> -1e30).
// Flash attention, swapped-QK^T (S^T = K.Q^T): softmax + O^T accum per-lane-q.
// R10 vs R6: (1) XCD-aware block mapping (b = wgid%16 -> all q-tiles of a batch
// on one XCD -> K/V L2-resident, mask stream can't force K/V to HBM);
// (2) double-buffered LDS (2x34KB), ONE barrier per KV-pair instead of two,
// WRITELDS(next) overlaps COMPUTE(cur) with no vmcnt(0)-into-barrier drain.

#define Bn   16
#define Qn   2048
#define Kseq 2048
#define Dn   64
#define QBLK 128
#define NEGF (-1e30f)
#define BUF1 34816          // byte offset of LDS buffer 1 (per-buffer size)

typedef __attribute__((ext_vector_type(4)))  short short4v;
typedef __attribute__((ext_vector_type(8)))  short short8;
typedef __attribute__((ext_vector_type(4)))  unsigned uint4v;
typedef __attribute__((ext_vector_type(16))) float f32x16;

static __device__ __forceinline__ short f2bf(float x) {
  union { float f; unsigned u; } un; un.f = x;          // scalar union: SROA-safe
  unsigned r = un.u + 0x7FFFu + ((un.u >> 16) & 1u);    // RNE
  return (short)(r >> 16);
}
static __device__ __forceinline__ unsigned pkbf(float lo, float hi) {
  unsigned r;
  asm("v_cvt_pk_bf16_f32 %0, %1, %2" : "=v"(r) : "v"(lo), "v"(hi));
  return r;
}
#if __has_builtin(__builtin_amdgcn_exp2f)
#define EXP2 __builtin_amdgcn_exp2f
#else
#define EXP2 exp2f
#endif
#define MFMA32 __builtin_amdgcn_mfma_f32_32x32x16_bf16

// ---- prefetch next pair: K 4xfloat4 chunk-linear, V 8xfloat2 row-pairs,
//      mask 2 passes x 4 consecutive int4 (512B run per 8-lane row group) ----
#define PREF_KV()                                                             \
  do {                                                                        \
    kst[0] = kp4[co0]; kst[1] = kp4[co1];                                     \
    kst[2] = kp4[co2]; kst[3] = kp4[co3];                                     \
    _Pragma("unroll")                                                         \
    for (int j2 = 0; j2 < 8; ++j2) vst[j2] = *(const float2*)(vp + j2 * 64);  \
    kp4 += 2048; vp += 8192;                                                  \
  } while (0)

#define PREF_M()                                                              \
  do {                                                                        \
    _Pragma("unroll")                                                         \
    for (int p = 0; p < 2; ++p)                                               \
      _Pragma("unroll")                                                       \
      for (int jj = 0; jj < 4; ++jj)                                          \
        mld[p * 4 + jj] = mpp[p * 32768 + jj];                                \
    mpp += 32;                                                                \
  } while (0)

// K/V -> LDS (bf16, swizzled) then mask compress -> LDS transpose buffer
#define WRITELDS(OFF)                                                         \
  do {                                                                        \
    _Pragma("unroll")                                                         \
    for (int i = 0; i < 4; ++i) {                                             \
      float4 a = kst[i]; short4v t;                                           \
      t[0] = f2bf(a.x); t[1] = f2bf(a.y); t[2] = f2bf(a.z); t[3] = f2bf(a.w); \
      *(short4v*)(kdst[i] + (OFF)) = t;                                       \
    }                                                                         \
    short8 v0, v1;                                                            \
    _Pragma("unroll")                                                         \
    for (int j2 = 0; j2 < 8; ++j2) { v0[j2] = f2bf(vst[j2].x); v1[j2] = f2bf(vst[j2].y); } \
    *(short8*)(vdst0 + (OFF)) = v0; *(short8*)(vdst1 + (OFF)) = v1;           \
    _Pragma("unroll")                                                         \
    for (int p = 0; p < 2; ++p) {                                             \
      unsigned v = 0;                                                         \
      _Pragma("unroll")                                                       \
      for (int jj = 0; jj < 4; ++jj) {                                        \
        int4 m = mld[p * 4 + jj];                                             \
        v |= (m.x != 0 ? 1u : 0u) << (jj * 4);                                \
        v |= (m.y != 0 ? 2u : 0u) << (jj * 4);                                \
        v |= (m.z != 0 ? 4u : 0u) << (jj * 4);                                \
        v |= (m.w != 0 ? 8u : 0u) << (jj * 4);                                \
      }                                                                       \
      *(unsigned short*)(mwrb + (OFF) + p * 1024) = (unsigned short)v;        \
    }                                                                         \
  } while (0)

// ---- one KV tile: mask bits from LDS, QK^T, mask, online softmax, pack, PV ----
#define COMPUTE(OFF)                                                          \
  do {                                                                        \
    const uint2 mb = *(const uint2*)(mrd + (OFF));                            \
    const unsigned xh = mb.x >> (4 * h);                                      \
    const unsigned yh = mb.y >> (4 * h);                                      \
    f32x16 st0, st1;                                                          \
    _Pragma("unroll")                                                         \
    for (int i = 0; i < 16; ++i) { st0[i] = 0.f; st1[i] = 0.f; }              \
    _Pragma("unroll")                                                         \
    for (int s = 0; s < 4; ++s) {                                             \
      short8 kf = *(const short8*)(krd + (OFF) + ((32 * s + hh) ^ swz));      \
      st0 = MFMA32(kf, qf[s], st0, 0, 0, 0);                                  \
      short8 kg = *(const short8*)(krd + (OFF) + 4096 + ((32 * s + hh) ^ swz));\
      st1 = MFMA32(kg, qf[s], st1, 0, 0, 0);                                  \
    }                                                                         \
    _Pragma("unroll")                                                         \
    for (int i = 0; i < 16; ++i) {                                            \
      const int bi = 8 * (i >> 2) + (i & 3);                                  \
      st0[i] = ((xh >> bi) & 1u) ? NEGF : st0[i];                             \
      st1[i] = ((yh >> bi) & 1u) ? NEGF : st1[i];                             \
    }                                                                         \
    float mx8[8];                                                             \
    _Pragma("unroll")                                                         \
    for (int i = 0; i < 8; ++i)                                               \
      mx8[i] = fmaxf(fmaxf(st0[i], st0[i+8]), fmaxf(st1[i], st1[i+8]));       \
    float mx = fmaxf(fmaxf(fmaxf(mx8[0],mx8[1]), fmaxf(mx8[2],mx8[3])),       \
                     fmaxf(fmaxf(mx8[4],mx8[5]), fmaxf(mx8[6],mx8[7])));      \
    mx = fmaxf(mx, __shfl_xor(mx, 32));                                       \
    if (!__all(mx <= mrun)) {                                                 \
      float mnew  = fmaxf(mrun, mx);                                          \
      float alpha = EXP2(mrun - mnew);                                        \
      lrun *= alpha;                                                          \
      _Pragma("unroll")                                                       \
      for (int i = 0; i < 16; ++i) { ot0[i] *= alpha; ot1[i] *= alpha; }      \
      mrun = mnew;                                                            \
    }                                                                         \
    _Pragma("unroll")                                                         \
    for (int i = 0; i < 16; ++i) {                                            \
      st0[i] = EXP2(st0[i] - mrun);                                           \
      st1[i] = EXP2(st1[i] - mrun);                                           \
    }                                                                         \
    float s8[8];                                                              \
    _Pragma("unroll")                                                         \
    for (int i = 0; i < 8; ++i) s8[i] = (st0[i]+st0[i+8]) + (st1[i]+st1[i+8]);\
    float lsum = ((s8[0]+s8[1]) + (s8[2]+s8[3])) +                            \
                 ((s8[4]+s8[5]) + (s8[6]+s8[7]));                             \
    lsum += __shfl_xor(lsum, 32);                                             \
    lrun += lsum;                                                             \
    short8 f0, f1, f2, f3;                                                    \
    {                                                                         \
      unsigned x0 = pkbf(st0[0],st0[1]),   x1 = pkbf(st0[2],st0[3]);          \
      unsigned y0 = pkbf(st0[4],st0[5]),   y1 = pkbf(st0[6],st0[7]);          \
      unsigned a0 = pkbf(st0[8],st0[9]),   a1 = pkbf(st0[10],st0[11]);        \
      unsigned b0 = pkbf(st0[12],st0[13]), b1 = pkbf(st0[14],st0[15]);        \
      unsigned sx0 = __shfl_xor(x0,32), sx1 = __shfl_xor(x1,32);              \
      unsigned sy0 = __shfl_xor(y0,32), sy1 = __shfl_xor(y1,32);              \
      unsigned sa0 = __shfl_xor(a0,32), sa1 = __shfl_xor(a1,32);              \
      unsigned sb0 = __shfl_xor(b0,32), sb1 = __shfl_xor(b1,32);              \
      uint4v u0 = { h ? sy0 : x0, h ? sy1 : x1, h ? y0 : sx0, h ? y1 : sx1 }; \
      uint4v u1 = { h ? sb0 : a0, h ? sb1 : a1, h ? b0 : sa0, h ? b1 : sa1 }; \
      f0 = __builtin_bit_cast(short8, u0);                                    \
      f1 = __builtin_bit_cast(short8, u1);                                    \
    }                                                                         \
    {                                                                         \
      unsigned x0 = pkbf(st1[0],st1[1]),   x1 = pkbf(st1[2],st1[3]);          \
      unsigned y0 = pkbf(st1[4],st1[5]),   y1 = pkbf(st1[6],st1[7]);          \
      unsigned a0 = pkbf(st1[8],st1[9]),   a1 = pkbf(st1[10],st1[11]);        \
      unsigned b0 = pkbf(st1[12],st1[13]), b1 = pkbf(st1[14],st1[15]);        \
      unsigned sx0 = __shfl_xor(x0,32), sx1 = __shfl_xor(x1,32);              \
      unsigned sy0 = __shfl_xor(y0,32), sy1 = __shfl_xor(y1,32);              \
      unsigned sa0 = __shfl_xor(a0,32), sa1 = __shfl_xor(a1,32);              \
      unsigned sb0 = __shfl_xor(b0,32), sb1 = __shfl_xor(b1,32);              \
      uint4v u2 = { h ? sy0 : x0, h ? sy1 : x1, h ? y0 : sx0, h ? y1 : sx1 }; \
      uint4v u3 = { h ? sb0 : a0, h ? sb1 : a1, h ? b0 : sa0, h ? b1 : sa1 }; \
      f2 = __builtin_bit_cast(short8, u2);                                    \
      f3 = __builtin_bit_cast(short8, u3);                                    \
    }                                                                         \
    _Pragma("unroll")                                                         \
    for (int s = 0; s < 4; ++s) {                                             \
      short8 pf = (s==0) ? f0 : (s==1) ? f1 : (s==2) ? f2 : f3;               \
      short8 va = *(const short8*)(vrd + (OFF) + ((32 * s + hh) ^ swz));      \
      ot0 = MFMA32(va, pf, ot0, 0, 0, 0);                                     \
      short8 vb = *(const short8*)(vrd + (OFF) + 4096 + ((32 * s + hh) ^ swz));\
      ot1 = MFMA32(vb, pf, ot1, 0, 0, 0);                                     \
    }                                                                         \
  } while (0)

__launch_bounds__(512, 2)
__global__ void attn_fused(const float* __restrict__ Qg,
                           const float* __restrict__ Kg,
                           const float* __restrict__ Vg,
                           const int*   __restrict__ Mg,
                           float* __restrict__ Og) {
  // two buffers of 34K: per buffer K pair [0,16K), V^T pair [16K,32K), mask [32K,34K)
  __shared__ char ldsb[2 * BUF1];

  const int tid  = threadIdx.x;
  const int lane = tid & 63;
  const int w    = tid >> 6;     // wave 0..7
  const int wq   = w & 3;        // q-subtile
  const int grp  = w >> 2;       // 0: even tiles, 1: odd tiles
  const int l31  = lane & 31;
  const int h    = lane >> 5;
  const int hh   = h << 4;
  const int swz  = (l31 & 7) << 4;
  // XCD-aware mapping: XCD = wgid % 8 (round-robin heuristic, correctness-
  // invariant). b = wgid & 15 pins all 16 q-tile blocks of a batch (and
  // batches b, b+8) to XCD b%8 -> K/V working set 4MB = L2-resident.
  const int wgid = blockIdx.x;
  const int b    = wgid & 15;
  const int qb   = (wgid >> 4) * QBLK;
  const int q    = qb + wq * 32 + l31;

  // ---- Q fragments (B-operand), log2(e)/sqrt(D) folded ----
  const float qscale = 0.18033688011112042f;   // log2(e)/8
  const float* qp = Qg + ((size_t)(b * Qn + q)) * Dn + 8 * h;
  short8 qf[4];
#pragma unroll
  for (int s = 0; s < 4; ++s) {
    float4 a = *(const float4*)(qp + 16 * s);
    float4 c = *(const float4*)(qp + 16 * s + 4);
    short8 f;
    f[0]=f2bf(a.x*qscale); f[1]=f2bf(a.y*qscale); f[2]=f2bf(a.z*qscale); f[3]=f2bf(a.w*qscale);
    f[4]=f2bf(c.x*qscale); f[5]=f2bf(c.y*qscale); f[6]=f2bf(c.z*qscale); f[7]=f2bf(c.w*qscale);
    qf[s] = f;
  }

  // ---- K staging: chunk-linear over the 128-row pair (fully coalesced) ----
  const float4* kp4 = (const float4*)(Kg + (size_t)b * Kseq * Dn);
  const int co0 = tid, co1 = tid + 512, co2 = tid + 1024, co3 = tid + 1536;
  char* kdst[4];
#pragma unroll
  for (int i = 0; i < 4; ++i) {
    int c = tid + 512 * i;
    int row = c >> 4, col16 = c & 15;        // row in pair (0..127), 16B col chunk
    int tile = row >> 6, r = row & 63;
    kdst[i] = ldsb + tile * 8192 + r * 128 +
              (((col16 >> 1) << 4) ^ ((r & 7) << 4)) + ((col16 & 1) << 3);
  }

  // ---- V staging: row-pair coalesced float2, transposed into V^T LDS ----
  const int uu = tid & 255, tileV = tid >> 8;
  const int d0 = (uu & 31) * 2, kv8 = (uu >> 5) * 8;
  const float* vp = Vg + ((size_t)b * Kseq + tileV * 64 + kv8) * Dn + d0;
  char* vdst0 = ldsb + 16384 + tileV * 8192 + d0 * 128 + ((kv8 * 2) ^ ((d0 & 7) << 4));
  char* vdst1 = ldsb + 16384 + tileV * 8192 + (d0 + 1) * 128 + ((kv8 * 2) ^ (((d0 + 1) & 7) << 4));

  // ---- mask staging: 8 lanes cover one row's 512B pair-span (coalesced) ----
  const int4* mpp = (const int4*)(Mg + ((size_t)(b * Qn + qb + (tid >> 3))) * Kseq)
                    + (tid & 7) * 4;
  char* mwrb = ldsb + 32768 + ((tid >> 3) * 8 + (tid & 7)) * 2;
  const char* mrd = ldsb + 32768 + (wq * 32 + l31) * 16 + grp * 8;

  // ---- LDS read bases (group-selected tile) ----
  const char* krd = ldsb + grp * 8192 + l31 * 128;
  const char* vrd = ldsb + 16384 + grp * 8192 + l31 * 128;

  // ---- state ----
  f32x16 ot0, ot1;
#pragma unroll
  for (int i = 0; i < 16; ++i) { ot0[i] = 0.f; ot1[i] = 0.f; }
  float mrun = NEGF, lrun = 0.f;

  float4 kst[4];
  float2 vst[8];
  int4   mld[8];

  // ---- prologue: pair 0 -> buf0; pair 1 loads in flight ----
  PREF_KV(); PREF_M();
  WRITELDS(0);
  PREF_KV(); PREF_M();
  __syncthreads();

#pragma unroll 1
  for (int t = 0; t < 8; ++t) {
    COMPUTE(0);                              // pair 2t   (buf0)
    WRITELDS(BUF1);                          // pair 2t+1 -> buf1
    if (t < 7) { PREF_KV(); PREF_M(); }      // pair 2t+2 in flight
    __syncthreads();
    COMPUTE(BUF1);                           // pair 2t+1 (buf1)
    if (t < 7) {
      WRITELDS(0);                           // pair 2t+2 -> buf0
      PREF_KV(); PREF_M();                   // pair 2t+3 in flight
      __syncthreads();
    }
  }
  // last COMPUTE read buf1; merge buffers below live in buf0 region -> no
  // extra barrier needed before overlaying them.

  // ---- merge the two KV-halves (wave w <- wave w+4), normalize, store ----
  float* lm = (float*)ldsb;                 // [4][64] running max (group B)
  float* ll = lm + 256;                     // [4][64] running sum
  float* lo = ll + 256;                     // [4][64][stride 20] O^T halves
  const int s4 = wq * 64 + lane;
  if (grp == 1) {
    lm[s4] = mrun; ll[s4] = lrun;
#pragma unroll
    for (int i = 0; i < 16; ++i) lo[s4 * 20 + i] = ot0[i];
  }
  __syncthreads();
  float aA = 1.f, aB = 0.f;
  if (grp == 0) {
    float mB = lm[s4], lB = ll[s4];
    float ms = fmaxf(mrun, mB);
    aA = EXP2(mrun - ms); aB = EXP2(mB - ms);
    lrun = lrun * aA + lB * aB;
#pragma unroll
    for (int i = 0; i < 16; ++i) ot0[i] = ot0[i] * aA + lo[s4 * 20 + i] * aB;
  }
  __syncthreads();
  if (grp == 1) {
#pragma unroll
    for (int i = 0; i < 16; ++i) lo[s4 * 20 + i] = ot1[i];
  }
  __syncthreads();
  if (grp == 0) {
#pragma unroll
    for (int i = 0; i < 16; ++i) ot1[i] = ot1[i] * aA + lo[s4 * 20 + i] * aB;
    float inv = 1.0f / lrun;
    float* op = Og + ((size_t)(b * Qn + q)) * Dn;
#pragma unroll
    for (int g = 0; g < 4; ++g) {
      float4 o;
      o.x = ot0[4*g+0] * inv; o.y = ot0[4*g+1] * inv;
      o.z = ot0[4*g+2] * inv; o.w = ot0[4*g+3] * inv;
      *(float4*)(op + 8*g + 4*h) = o;
      o.x = ot1[4*g+0] * inv; o.y = ot1[4*g+1] * inv;
      o.z = ot1[4*g+2] * inv; o.w = ot1[4*g+3] * inv;
      *(float4*)(op + 32 + 8*g + 4*h) = o;
    }
  }
}

extern "C" void kernel_launch(void* const* d_in, const int* in_sizes, int n_in,
                              void* d_out, int out_size, void* d_ws, size_t ws_size,
                              hipStream_t stream) {
  const float* Q = (const float*)d_in[0];
  const float* K = (const float*)d_in[1];
  const float* V = (const float*)d_in[2];
  const int*   M = (const int*)d_in[3];
  float* O = (float*)d_out;
  attn_fused<<<dim3(256), dim3(512), 0, stream>>>(Q, K, V, M, O);
}